// Round 2
// baseline (354.685 us; speedup 1.0000x reference)
//
#include <hip/hip_runtime.h>

// out[b,s] = capped_relu( sum_c x[b,c,s] * W[c,s] + bias[s] )
// B=64, C=256, S=4096, all float32.
// Memory-bound: x is 256 MiB streamed once; W (4 MiB) is L2/L3-resident.

#define BATCH    64
#define CHANNELS 256
#define SIZE     4096

__device__ __forceinline__ float capped_relu(float v) {
    return (v > 0.0f && v <= 1.0f) ? v : 0.0f;
}

__global__ __launch_bounds__(256) void CWG_30794915512765_kernel(
    const float* __restrict__ x,
    const float* __restrict__ w,
    const float* __restrict__ bias,
    float* __restrict__ out)
{
    // 4 s-tiles of 1024 per batch row; block = 256 threads x float4 = 1024 s.
    const int bid = blockIdx.x;
    const int b   = bid >> 2;
    const int s   = ((bid & 3) << 10) + (threadIdx.x << 2);

    const float* xcol = x + (size_t)b * CHANNELS * SIZE + s;
    const float* wcol = w + s;

    float4 acc = make_float4(0.0f, 0.0f, 0.0f, 0.0f);

#pragma unroll 8
    for (int c = 0; c < CHANNELS; ++c) {
        const float4 xv = *reinterpret_cast<const float4*>(xcol + (size_t)c * SIZE);
        const float4 wv = *reinterpret_cast<const float4*>(wcol + (size_t)c * SIZE);
        acc.x += xv.x * wv.x;
        acc.y += xv.y * wv.y;
        acc.z += xv.z * wv.z;
        acc.w += xv.w * wv.w;
    }

    const float4 bv = *reinterpret_cast<const float4*>(bias + s);
    float4 o;
    o.x = capped_relu(acc.x + bv.x);
    o.y = capped_relu(acc.y + bv.y);
    o.z = capped_relu(acc.z + bv.z);
    o.w = capped_relu(acc.w + bv.w);

    *reinterpret_cast<float4*>(out + (size_t)b * SIZE + s) = o;
}

extern "C" void kernel_launch(void* const* d_in, const int* in_sizes, int n_in,
                              void* d_out, int out_size, void* d_ws, size_t ws_size,
                              hipStream_t stream) {
    const float* x    = (const float*)d_in[0];
    const float* w    = (const float*)d_in[1];
    const float* bias = (const float*)d_in[2];
    float* out        = (float*)d_out;

    const int blocks = BATCH * (SIZE / 1024);  // 64 * 4 = 256
    CWG_30794915512765_kernel<<<blocks, 256, 0, stream>>>(x, w, bias, out);
}